// Round 2
// baseline (185.534 us; speedup 1.0000x reference)
//
#include <hip/hip_runtime.h>
#include <math.h>

// Problem constants: B=4, C=128, H=W=96, E=4, C8=16, scale=2 (baked in)
#define Bn 4
#define Cc 128
#define Hh 96
#define Ww 96
#define H2c 192
#define W2c 192
#define HW (Hh*Ww)

// Workspace layout (floats):
//   [0, COMP_F)              comp[b][y][o][x]   (4*192*16*192 = 2359296 floats, 9.44 MB)
//   [WC_OFF, +4*2048)        Wc_mix[cls][o][c]  (16x128 per class)
//   [WE_OFF, +4*2048)        We_mix[cls][c][o]  (128x16 per class)
//   [TAP_OFF, +16)           per-class {tx, ty, Dx, Dy}
#define COMP_F (Bn*H2c*16*W2c)
#define WC_OFF COMP_F
#define WE_OFF (COMP_F + 4*2048)
#define TAP_OFF (COMP_F + 8*2048)
// total = COMP_F + 16400 floats ~= 9.50 MB of d_ws

// ---------------------------------------------------------------------------
// K1: per-class tiny MLP -> routing/offsets; mix expert weights; tap constants.
// grid = 64 blocks (4 classes x 16 chunks), 256 threads.
// MLP recomputed redundantly per block (trivial cost) to keep one launch.
__global__ __launch_bounds__(256) void k1_mix(
    const float* __restrict__ wcomp, const float* __restrict__ wexp,
    const float* __restrict__ bw1, const float* __restrict__ bb1,
    const float* __restrict__ bw2, const float* __restrict__ bb2,
    const float* __restrict__ rw,  const float* __restrict__ rb,
    const float* __restrict__ ow,  const float* __restrict__ ob,
    float* __restrict__ ws)
{
    __shared__ float e1[64], e2[64], rr[4], of[2];
    const int tid   = threadIdx.x;
    const int cls   = blockIdx.x >> 4;   // pcy*2 + pcx
    const int chunk = blockIdx.x & 15;
    const float chv = (cls & 2) ? 0.25f : -0.25f;  // row fractional coord
    const float cwv = (cls & 1) ? 0.25f : -0.25f;  // col fractional coord

    if (tid < 64) {
        float h = bw1[tid*3+0]*0.5f + bw1[tid*3+1]*chv + bw1[tid*3+2]*cwv + bb1[tid];
        e1[tid] = fmaxf(h, 0.f);
    }
    __syncthreads();
    if (tid < 64) {
        float s = bb2[tid];
        for (int i = 0; i < 64; ++i) s += bw2[tid*64+i]*e1[i];
        e2[tid] = fmaxf(s, 0.f);
    }
    __syncthreads();
    if (tid < 6) {
        if (tid < 4) {
            float s = rb[tid];
            for (int i = 0; i < 64; ++i) s += rw[tid*64+i]*e2[i];
            rr[tid] = 1.f/(1.f+expf(-s));
        } else {
            const int d = tid - 4;
            float s = ob[d];
            for (int i = 0; i < 64; ++i) s += ow[d*64+i]*e2[i];
            of[d] = s;
        }
    }
    __syncthreads();
    const float r0 = rr[0], r1 = rr[1], r2 = rr[2], r3 = rr[3];

    const int idx = chunk*128 + (tid & 127);
    if (tid < 128) {
        ws[WC_OFF + cls*2048 + idx] =
            r0*wcomp[idx] + r1*wcomp[2048+idx] + r2*wcomp[4096+idx] + r3*wcomp[6144+idx];
    } else {
        ws[WE_OFF + cls*2048 + idx] =
            r0*wexp[idx]  + r1*wexp[2048+idx]  + r2*wexp[4096+idx]  + r3*wexp[6144+idx];
    }
    if (chunk == 0 && tid == 0) {
        // ix = k + fx for x = 2k+pcx (exact: k integer + class-const fraction)
        const float fx = cwv + of[0];
        const float fy = chv + of[1];
        const float Dx = floorf(fx), Dy = floorf(fy);
        ws[TAP_OFF + cls*4 + 0] = fx - Dx;
        ws[TAP_OFF + cls*4 + 1] = fy - Dy;
        ws[TAP_OFF + cls*4 + 2] = Dx;
        ws[TAP_OFF + cls*4 + 3] = Dy;
    }
}

// Edge remap: taps at c0, c0+1 clamped to a 2-wide window [base, base+1] with
// zero-padding folded into the two weights.
__device__ __forceinline__ void remap_axis(int c0, int last, float w0, float w1,
                                           int& base, float& a0, float& a1)
{
    base = min(max(c0, 0), last - 1);          // 0..last-1 (window start)
    if (c0 >= 0 && c0 < last) { a0 = w0;  a1 = w1;  }
    else if (c0 == -1)        { a0 = w1;  a1 = 0.f; }   // only tap1 valid = col 0
    else if (c0 == last)      { a0 = 0.f; a1 = w0;  }   // only tap0 valid = col last
    else                      { a0 = 0.f; a1 = 0.f; }
}

// ---------------------------------------------------------------------------
// K2: comp[b][y][o][x] = Wc_mix[cls] . bilinear(x). grid (192, 4), 192 thr.
__global__ __launch_bounds__(192) void k2_compress(
    const float* __restrict__ x, const float* __restrict__ wsr, float* __restrict__ wsw)
{
    const int xg = threadIdx.x;
    const int y  = blockIdx.x;
    const int b  = blockIdx.y;
    const int cls = ((y & 1) << 1) | (xg & 1);

    const float tx = wsr[TAP_OFF + cls*4 + 0];
    const float ty = wsr[TAP_OFF + cls*4 + 1];
    const int   Dx = (int)wsr[TAP_OFF + cls*4 + 2];
    const int   Dy = (int)wsr[TAP_OFF + cls*4 + 3];

    int cb, rbw; float ax0, ax1, ay0, ay1;
    remap_axis((xg >> 1) + Dx, Ww - 1, 1.f - tx, tx, cb,  ax0, ax1);
    remap_axis((y  >> 1) + Dy, Hh - 1, 1.f - ty, ty, rbw, ay0, ay1);
    const float w00 = ay0*ax0, w01 = ay0*ax1, w10 = ay1*ax0, w11 = ay1*ax1;

    const float* xb = x + (size_t)b*Cc*HW + (rbw*Ww + cb);
    const float* Wc = wsr + WC_OFF + cls*2048;

    float comp[16];
    #pragma unroll
    for (int o = 0; o < 16; ++o) comp[o] = 0.f;

    for (int c0 = 0; c0 < Cc; c0 += 4) {
        float fea[4];
        #pragma unroll
        for (int q = 0; q < 4; ++q) {
            const float* p = xb + (size_t)(c0 + q)*HW;
            const float v00 = p[0], v01 = p[1], v10 = p[Ww], v11 = p[Ww+1];
            fea[q] = w00*v00 + w01*v01 + w10*v10 + w11*v11;
        }
        #pragma unroll
        for (int o = 0; o < 16; ++o) {
            const float4 w = *reinterpret_cast<const float4*>(Wc + o*128 + c0);
            comp[o] += w.x*fea[0] + w.y*fea[1] + w.z*fea[2] + w.w*fea[3];
        }
    }
    float* cw = wsw + ((size_t)(b*H2c + y)*16)*W2c + xg;
    #pragma unroll
    for (int o = 0; o < 16; ++o) cw[(size_t)o*W2c] = comp[o];
}

// ---------------------------------------------------------------------------
// K3: out = We_mix . comp + fea0 (residual). grid (192, 4, 8), 192 thr.
// Each thread: one pixel x 16 channels. Dominant, write-bound kernel.
__global__ __launch_bounds__(192) void k3_expand(
    const float* __restrict__ x, const float* __restrict__ wsr, float* __restrict__ out)
{
    const int xg = threadIdx.x;
    const int y  = blockIdx.x;
    const int b  = blockIdx.y;
    const int cg = blockIdx.z;       // channel group of 16
    const int cls = ((y & 1) << 1) | (xg & 1);

    const float tx = wsr[TAP_OFF + cls*4 + 0];
    const float ty = wsr[TAP_OFF + cls*4 + 1];
    const int   Dx = (int)wsr[TAP_OFF + cls*4 + 2];
    const int   Dy = (int)wsr[TAP_OFF + cls*4 + 3];

    int cb, rbw; float ax0, ax1, ay0, ay1;
    remap_axis((xg >> 1) + Dx, Ww - 1, 1.f - tx, tx, cb,  ax0, ax1);
    remap_axis((y  >> 1) + Dy, Hh - 1, 1.f - ty, ty, rbw, ay0, ay1);
    const float w00 = ay0*ax0, w01 = ay0*ax1, w10 = ay1*ax0, w11 = ay1*ax1;

    float comp[16];
    const float* cr = wsr + ((size_t)(b*H2c + y)*16)*W2c + xg;
    #pragma unroll
    for (int o = 0; o < 16; ++o) comp[o] = cr[(size_t)o*W2c];

    const float* xb = x + (size_t)b*Cc*HW + (rbw*Ww + cb);
    const float* We = wsr + WE_OFF + cls*2048;
    float* ob_ = out + ((size_t)(b*Cc + cg*16)*H2c + y)*W2c + xg;

    #pragma unroll 4
    for (int q = 0; q < 16; ++q) {
        const int c = cg*16 + q;
        const float* p = xb + (size_t)c*HW;
        const float v00 = p[0], v01 = p[1], v10 = p[Ww], v11 = p[Ww+1];
        float acc = w00*v00 + w01*v01 + w10*v10 + w11*v11;   // fea0 residual
        #pragma unroll
        for (int og = 0; og < 4; ++og) {
            const float4 w = *reinterpret_cast<const float4*>(We + c*16 + og*4);
            acc += w.x*comp[og*4+0] + w.y*comp[og*4+1]
                 + w.z*comp[og*4+2] + w.w*comp[og*4+3];
        }
        ob_[(size_t)q*H2c*W2c] = acc;
    }
}

extern "C" void kernel_launch(void* const* d_in, const int* in_sizes, int n_in,
                              void* d_out, int out_size, void* d_ws, size_t ws_size,
                              hipStream_t stream) {
    const float* x     = (const float*)d_in[0];
    const float* wcomp = (const float*)d_in[1];
    const float* wexp  = (const float*)d_in[2];
    const float* bw1   = (const float*)d_in[3];
    const float* bb1   = (const float*)d_in[4];
    const float* bw2   = (const float*)d_in[5];
    const float* bb2   = (const float*)d_in[6];
    const float* rw    = (const float*)d_in[7];
    const float* rb    = (const float*)d_in[8];
    const float* ow    = (const float*)d_in[9];
    const float* ob    = (const float*)d_in[10];
    float* out = (float*)d_out;
    float* ws  = (float*)d_ws;   // needs ~9.51 MB

    k1_mix<<<64, 256, 0, stream>>>(wcomp, wexp, bw1, bb1, bw2, bb2, rw, rb, ow, ob, ws);
    k2_compress<<<dim3(H2c, Bn), 192, 0, stream>>>(x, ws, ws);
    k3_expand<<<dim3(H2c, Bn, 8), 192, 0, stream>>>(x, ws, out);
}

// Round 3
// 98.740 us; speedup vs baseline: 1.8790x; 1.8790x over previous
//
#include <hip/hip_runtime.h>
#include <math.h>

// Problem constants: B=4, C=128, H=W=96, E=4, C8=16, scale=2 (baked in)
#define Bn 4
#define Cc 128
#define Hh 96
#define Ww 96
#define H2c 192
#define W2c 192
#define HW (Hh*Ww)

// Workspace layout (floats): tiny — only mixed weights + taps.
//   [WC_OFF, +4*2048)  Wc_t[cls][c][o]  (transposed: c-major, 16 o contiguous)
//   [WE_OFF, +4*2048)  We_t[cls][c][o]  (native wexp layout)
//   [TAP_OFF, +16)     per-class {tx, ty, Dx, Dy}
#define WC_OFF 0
#define WE_OFF (4*2048)
#define TAP_OFF (8*2048)

// ---------------------------------------------------------------------------
// K1: per-class tiny MLP -> routing/offsets; mix expert weights; tap constants.
__global__ __launch_bounds__(256) void k1_mix(
    const float* __restrict__ wcomp, const float* __restrict__ wexp,
    const float* __restrict__ bw1, const float* __restrict__ bb1,
    const float* __restrict__ bw2, const float* __restrict__ bb2,
    const float* __restrict__ rw,  const float* __restrict__ rb,
    const float* __restrict__ ow,  const float* __restrict__ ob,
    float* __restrict__ ws)
{
    __shared__ float e1[64], e2[64], rr[4], of[2];
    const int tid   = threadIdx.x;
    const int cls   = blockIdx.x >> 4;   // pcy*2 + pcx
    const int chunk = blockIdx.x & 15;
    const float chv = (cls & 2) ? 0.25f : -0.25f;  // row fractional coord
    const float cwv = (cls & 1) ? 0.25f : -0.25f;  // col fractional coord

    if (tid < 64) {
        float h = bw1[tid*3+0]*0.5f + bw1[tid*3+1]*chv + bw1[tid*3+2]*cwv + bb1[tid];
        e1[tid] = fmaxf(h, 0.f);
    }
    __syncthreads();
    if (tid < 64) {
        float s = bb2[tid];
        for (int i = 0; i < 64; ++i) s += bw2[tid*64+i]*e1[i];
        e2[tid] = fmaxf(s, 0.f);
    }
    __syncthreads();
    if (tid < 6) {
        if (tid < 4) {
            float s = rb[tid];
            for (int i = 0; i < 64; ++i) s += rw[tid*64+i]*e2[i];
            rr[tid] = 1.f/(1.f+expf(-s));
        } else {
            const int d = tid - 4;
            float s = ob[d];
            for (int i = 0; i < 64; ++i) s += ow[d*64+i]*e2[i];
            of[d] = s;
        }
    }
    __syncthreads();
    const float r0 = rr[0], r1 = rr[1], r2 = rr[2], r3 = rr[3];

    if (tid < 128) {
        // Wc: source [o][c] (idx = o*128+c), dest transposed [c][o]
        const int idx = chunk*128 + tid;
        const int o = idx >> 7, c = idx & 127;
        const float v = r0*wcomp[idx] + r1*wcomp[2048+idx]
                      + r2*wcomp[4096+idx] + r3*wcomp[6144+idx];
        ws[WC_OFF + cls*2048 + c*16 + o] = v;
    } else {
        // We: native [c][o] layout, straight copy of the mix
        const int idx = chunk*128 + (tid - 128);
        ws[WE_OFF + cls*2048 + idx] =
            r0*wexp[idx] + r1*wexp[2048+idx] + r2*wexp[4096+idx] + r3*wexp[6144+idx];
    }
    if (chunk == 0 && tid == 0) {
        const float fx = cwv + of[0];
        const float fy = chv + of[1];
        const float Dx = floorf(fx), Dy = floorf(fy);
        ws[TAP_OFF + cls*4 + 0] = fx - Dx;
        ws[TAP_OFF + cls*4 + 1] = fy - Dy;
        ws[TAP_OFF + cls*4 + 2] = Dx;
        ws[TAP_OFF + cls*4 + 3] = Dy;
    }
}

// Edge remap: taps at c0, c0+1 clamped to 2-wide window [base, base+1], with
// zero-padding folded into the two weights. (Verified in round 1/2.)
__device__ __forceinline__ void remap_axis(int c0, int last, float w0, float w1,
                                           int& base, float& a0, float& a1)
{
    base = min(max(c0, 0), last - 1);
    if (c0 >= 0 && c0 < last) { a0 = w0;  a1 = w1;  }
    else if (c0 == -1)        { a0 = w1;  a1 = 0.f; }
    else if (c0 == last)      { a0 = 0.f; a1 = w0;  }
    else                      { a0 = 0.f; a1 = 0.f; }
}

// ---------------------------------------------------------------------------
// Fused compress+expand. grid (3, 192, 4), 256 threads = 4 waves.
// Wave g owns channels [g*32, g*32+32); thread = (xl, g). fea kept in VGPRs.
__global__ __launch_bounds__(256, 4) void k2_fused(
    const float* __restrict__ x, const float* __restrict__ wsr,
    float* __restrict__ out)
{
    __shared__ __align__(16) float lWc[2*2048];    // [clsL][c*16+o]  16 KB
    __shared__ float lPart[4*16*64];               // [g][o][xl]      16 KB
    __shared__ float lComp[16*64];                 // [o][xl]          4 KB

    const int tid = threadIdx.x;
    const int xl  = tid & 63;
    const int grp = tid >> 6;
    const int y   = blockIdx.y;
    const int b   = blockIdx.z;
    const int xg  = blockIdx.x*64 + xl;
    const int clsL = xl & 1;
    const int clsG = ((y & 1) << 1) | clsL;

    // stage Wc for this row's two x-parity classes (coalesced float4 copy)
    {
        const float4* src = reinterpret_cast<const float4*>(
            wsr + WC_OFF + ((y & 1) << 1)*2048);
        float4* dst = reinterpret_cast<float4*>(lWc);
        #pragma unroll
        for (int i = 0; i < 4; ++i) dst[tid + i*256] = src[tid + i*256];
    }

    const float tx = wsr[TAP_OFF + clsG*4 + 0];
    const float ty = wsr[TAP_OFF + clsG*4 + 1];
    const int   Dx = (int)wsr[TAP_OFF + clsG*4 + 2];
    const int   Dy = (int)wsr[TAP_OFF + clsG*4 + 3];
    int cb, rbw; float ax0, ax1, ay0, ay1;
    remap_axis((xg >> 1) + Dx, Ww - 1, 1.f - tx, tx, cb,  ax0, ax1);
    remap_axis((y  >> 1) + Dy, Hh - 1, 1.f - ty, ty, rbw, ay0, ay1);
    const float w00 = ay0*ax0, w01 = ay0*ax1, w10 = ay1*ax0, w11 = ay1*ax1;
    const float* xb = x + (size_t)b*Cc*HW + rbw*Ww + cb;
    __syncthreads();

    // ---- P1: partial compress over this wave's 32 channels; fea -> VGPRs ----
    float comp[16];
    #pragma unroll
    for (int o = 0; o < 16; ++o) comp[o] = 0.f;
    float fea[32];
    const float* wcl = lWc + clsL*2048;

    #pragma unroll
    for (int k = 0; k < 32; ++k) {
        const int c = grp*32 + k;
        const float* p = xb + (size_t)c*HW;
        const float f = w00*p[0] + w01*p[1] + w10*p[Ww] + w11*p[Ww+1];
        fea[k] = f;
        const float4* wq = reinterpret_cast<const float4*>(wcl + c*16);
        const float4 q0 = wq[0], q1 = wq[1], q2 = wq[2], q3 = wq[3];
        comp[ 0] += q0.x*f; comp[ 1] += q0.y*f; comp[ 2] += q0.z*f; comp[ 3] += q0.w*f;
        comp[ 4] += q1.x*f; comp[ 5] += q1.y*f; comp[ 6] += q1.z*f; comp[ 7] += q1.w*f;
        comp[ 8] += q2.x*f; comp[ 9] += q2.y*f; comp[10] += q2.z*f; comp[11] += q2.w*f;
        comp[12] += q3.x*f; comp[13] += q3.y*f; comp[14] += q3.z*f; comp[15] += q3.w*f;
    }
    #pragma unroll
    for (int o = 0; o < 16; ++o) lPart[(grp*16 + o)*64 + xl] = comp[o];
    __syncthreads();

    // ---- deterministic cross-wave reduce: thread handles o = grp*4..+3 ----
    #pragma unroll
    for (int j = 0; j < 4; ++j) {
        const int o = grp*4 + j;
        lComp[o*64 + xl] = lPart[(o     )*64 + xl] + lPart[(16 + o)*64 + xl]
                         + lPart[(32 + o)*64 + xl] + lPart[(48 + o)*64 + xl];
    }
    __syncthreads();

    // ---- P2: expand + residual (fea from regs), We via wave-uniform loads ----
    float cf[16];
    #pragma unroll
    for (int j = 0; j < 16; ++j) cf[j] = lComp[j*64 + xl];

    const float* wep = wsr + WE_OFF + clsG*2048;
    float* op = out + ((size_t)(b*Cc)*H2c + y)*W2c + xg;

    #pragma unroll
    for (int k = 0; k < 32; ++k) {
        const int c = grp*32 + k;
        const float4* wq = reinterpret_cast<const float4*>(wep + c*16);
        const float4 q0 = wq[0], q1 = wq[1], q2 = wq[2], q3 = wq[3];
        float acc = fea[k]
            + q0.x*cf[ 0] + q0.y*cf[ 1] + q0.z*cf[ 2] + q0.w*cf[ 3]
            + q1.x*cf[ 4] + q1.y*cf[ 5] + q1.z*cf[ 6] + q1.w*cf[ 7]
            + q2.x*cf[ 8] + q2.y*cf[ 9] + q2.z*cf[10] + q2.w*cf[11]
            + q3.x*cf[12] + q3.y*cf[13] + q3.z*cf[14] + q3.w*cf[15];
        op[(size_t)c*(H2c*W2c)] = acc;
    }
}

extern "C" void kernel_launch(void* const* d_in, const int* in_sizes, int n_in,
                              void* d_out, int out_size, void* d_ws, size_t ws_size,
                              hipStream_t stream) {
    const float* x     = (const float*)d_in[0];
    const float* wcomp = (const float*)d_in[1];
    const float* wexp  = (const float*)d_in[2];
    const float* bw1   = (const float*)d_in[3];
    const float* bb1   = (const float*)d_in[4];
    const float* bw2   = (const float*)d_in[5];
    const float* bb2   = (const float*)d_in[6];
    const float* rw    = (const float*)d_in[7];
    const float* rb    = (const float*)d_in[8];
    const float* ow    = (const float*)d_in[9];
    const float* ob    = (const float*)d_in[10];
    float* out = (float*)d_out;
    float* ws  = (float*)d_ws;   // needs only ~66 KB

    k1_mix<<<64, 256, 0, stream>>>(wcomp, wexp, bw1, bb1, bw2, bb2, rw, rb, ow, ob, ws);
    k2_fused<<<dim3(3, H2c, Bn), 256, 0, stream>>>(x, ws, out);
}

// Round 4
// 43.193 us; speedup vs baseline: 4.2955x; 2.2860x over previous
//
#include <hip/hip_runtime.h>
#include <math.h>

// Problem constants: B=4, C=128, H=W=96, E=4, C8=16, scale=2 (baked in)
#define Bn 4
#define Cc 128
#define Hh 96
#define Ww 96
#define H2c 192
#define W2c 192
#define HW (Hh*Ww)

// Workspace layout (floats):
//   [WC_OFF, +4*2048)  Wc_t[cls][c][o]  (transposed: c-major, 16 o contiguous)
//   [WE_OFF, +4*2048)  We  [cls][c][o]  (native wexp layout)
//   [TAP_OFF, +16)     per-class {tx, ty, Dx, Dy}
#define WC_OFF 0
#define WE_OFF (4*2048)
#define TAP_OFF (8*2048)

// ---------------------------------------------------------------------------
// K1: per-class tiny MLP -> routing/offsets; mix expert weights; tap constants.
__global__ __launch_bounds__(256) void k1_mix(
    const float* __restrict__ wcomp, const float* __restrict__ wexp,
    const float* __restrict__ bw1, const float* __restrict__ bb1,
    const float* __restrict__ bw2, const float* __restrict__ bb2,
    const float* __restrict__ rw,  const float* __restrict__ rb,
    const float* __restrict__ ow,  const float* __restrict__ ob,
    float* __restrict__ ws)
{
    __shared__ float e1[64], e2[64], rr[4], of[2];
    const int tid   = threadIdx.x;
    const int cls   = blockIdx.x >> 4;   // pcy*2 + pcx
    const int chunk = blockIdx.x & 15;
    const float chv = (cls & 2) ? 0.25f : -0.25f;  // row fractional coord
    const float cwv = (cls & 1) ? 0.25f : -0.25f;  // col fractional coord

    if (tid < 64) {
        float h = bw1[tid*3+0]*0.5f + bw1[tid*3+1]*chv + bw1[tid*3+2]*cwv + bb1[tid];
        e1[tid] = fmaxf(h, 0.f);
    }
    __syncthreads();
    if (tid < 64) {
        float s = bb2[tid];
        for (int i = 0; i < 64; ++i) s += bw2[tid*64+i]*e1[i];
        e2[tid] = fmaxf(s, 0.f);
    }
    __syncthreads();
    if (tid < 6) {
        if (tid < 4) {
            float s = rb[tid];
            for (int i = 0; i < 64; ++i) s += rw[tid*64+i]*e2[i];
            rr[tid] = 1.f/(1.f+expf(-s));
        } else {
            const int d = tid - 4;
            float s = ob[d];
            for (int i = 0; i < 64; ++i) s += ow[d*64+i]*e2[i];
            of[d] = s;
        }
    }
    __syncthreads();
    const float r0 = rr[0], r1 = rr[1], r2 = rr[2], r3 = rr[3];

    if (tid < 128) {
        // Wc: source [o][c] (idx = o*128+c), dest transposed [c][o]
        const int idx = chunk*128 + tid;
        const int o = idx >> 7, c = idx & 127;
        const float v = r0*wcomp[idx] + r1*wcomp[2048+idx]
                      + r2*wcomp[4096+idx] + r3*wcomp[6144+idx];
        ws[WC_OFF + cls*2048 + c*16 + o] = v;
    } else {
        // We: native [c][o] layout, straight copy of the mix
        const int idx = chunk*128 + (tid - 128);
        ws[WE_OFF + cls*2048 + idx] =
            r0*wexp[idx] + r1*wexp[2048+idx] + r2*wexp[4096+idx] + r3*wexp[6144+idx];
    }
    if (chunk == 0 && tid == 0) {
        const float fx = cwv + of[0];
        const float fy = chv + of[1];
        const float Dx = floorf(fx), Dy = floorf(fy);
        ws[TAP_OFF + cls*4 + 0] = fx - Dx;
        ws[TAP_OFF + cls*4 + 1] = fy - Dy;
        ws[TAP_OFF + cls*4 + 2] = Dx;
        ws[TAP_OFF + cls*4 + 3] = Dy;
    }
}

// Edge remap: taps at c0, c0+1 clamped to 2-wide window [base, base+1], with
// zero-padding folded into the two weights. (Verified rounds 1-3.)
__device__ __forceinline__ void remap_axis(int c0, int last, float w0, float w1,
                                           int& base, float& a0, float& a1)
{
    base = min(max(c0, 0), last - 1);
    if (c0 >= 0 && c0 < last) { a0 = w0;  a1 = w1;  }
    else if (c0 == -1)        { a0 = w1;  a1 = 0.f; }
    else if (c0 == last)      { a0 = 0.f; a1 = w0;  }
    else                      { a0 = 0.f; a1 = 0.f; }
}

// ---------------------------------------------------------------------------
// Fused compress+expand, class-pure blocks.
// 2304 blocks x 256 threads (4 waves). Block = 64 consecutive pixels of the
// 96x96 half-res grid of ONE class; wave g owns channels [g*32, g*32+32).
// XCD swizzle: the 4 classes of a tile land consecutively on ONE XCD so their
// stride-2 stores merge in L2 and shared x rows are fetched once.
__global__ __launch_bounds__(256) void k2_fused(
    const float* __restrict__ x, const float* __restrict__ wsr,
    float* __restrict__ out)
{
    __shared__ __align__(16) float lWc[2048];      // [c][o] 8 KB (this class)
    __shared__ __align__(16) float lWe[2048];      // [c][o] 8 KB
    __shared__ float lPart[4*16*64];               // [g][o][xl] 16 KB (reused for comp)

    const int tid = threadIdx.x;
    const int xl  = tid & 63;
    const int grp = tid >> 6;

    // XCD-paired swizzle: 2304 = 8 XCDs * 288 slots
    const int n = blockIdx.x;
    const int w = (n & 7) * 288 + (n >> 3);
    const int px = w & 1, py = (w >> 1) & 1;
    const int w2 = w >> 2;            // 0..575
    const int tile = w2 % 144;        // spatial tile (b adjacent-ish per XCD)
    const int b    = w2 / 144;
    const int cls  = (py << 1) | px;

    // stage this class's weights (coalesced float4, 2 per thread each)
    {
        const float4* sc = reinterpret_cast<const float4*>(wsr + WC_OFF + cls*2048);
        const float4* se = reinterpret_cast<const float4*>(wsr + WE_OFF + cls*2048);
        float4* dc = reinterpret_cast<float4*>(lWc);
        float4* de = reinterpret_cast<float4*>(lWe);
        dc[tid] = sc[tid]; dc[tid+256] = sc[tid+256];
        de[tid] = se[tid]; de[tid+256] = se[tid+256];
    }

    // pixel decode: flat index in 96x96 half-res grid
    const int idx = tile*64 + xl;
    const int j = idx / 96;           // half-res row
    const int i = idx - j*96;         // half-res col

    const float tx = wsr[TAP_OFF + cls*4 + 0];
    const float ty = wsr[TAP_OFF + cls*4 + 1];
    const int   Dx = (int)wsr[TAP_OFF + cls*4 + 2];
    const int   Dy = (int)wsr[TAP_OFF + cls*4 + 3];
    int cb, rbw; float ax0, ax1, ay0, ay1;
    remap_axis(i + Dx, Ww - 1, 1.f - tx, tx, cb,  ax0, ax1);
    remap_axis(j + Dy, Hh - 1, 1.f - ty, ty, rbw, ay0, ay1);
    const float w00 = ay0*ax0, w01 = ay0*ax1, w10 = ay1*ax0, w11 = ay1*ax1;
    const float* xb = x + (size_t)b*Cc*HW + rbw*Ww + cb;
    __syncthreads();

    // ---- P1: partial compress over this wave's 32 channels; fea -> VGPRs ----
    float comp[16];
    #pragma unroll
    for (int o = 0; o < 16; ++o) comp[o] = 0.f;
    float fea[32];

    #pragma unroll
    for (int kk = 0; kk < 32; ++kk) {
        const int c = grp*32 + kk;
        const float* p = xb + (size_t)c*HW;
        const float f = w00*p[0] + w01*p[1] + w10*p[Ww] + w11*p[Ww+1];
        fea[kk] = f;
        const float4* wq = reinterpret_cast<const float4*>(lWc + c*16);  // wave-uniform
        const float4 q0 = wq[0], q1 = wq[1], q2 = wq[2], q3 = wq[3];
        comp[ 0] += q0.x*f; comp[ 1] += q0.y*f; comp[ 2] += q0.z*f; comp[ 3] += q0.w*f;
        comp[ 4] += q1.x*f; comp[ 5] += q1.y*f; comp[ 6] += q1.z*f; comp[ 7] += q1.w*f;
        comp[ 8] += q2.x*f; comp[ 9] += q2.y*f; comp[10] += q2.z*f; comp[11] += q2.w*f;
        comp[12] += q3.x*f; comp[13] += q3.y*f; comp[14] += q3.z*f; comp[15] += q3.w*f;
    }
    #pragma unroll
    for (int o = 0; o < 16; ++o) lPart[(grp*16 + o)*64 + xl] = comp[o];
    __syncthreads();

    // ---- cross-wave reduce; result lands in lPart's g=0 region (aliasing safe:
    // each (o,xl) g=0 slot is read as the g=0 term and rewritten by the SAME thread)
    #pragma unroll
    for (int jj = 0; jj < 4; ++jj) {
        const int o = grp*4 + jj;
        const float s = lPart[(o     )*64 + xl] + lPart[(16 + o)*64 + xl]
                      + lPart[(32 + o)*64 + xl] + lPart[(48 + o)*64 + xl];
        lPart[o*64 + xl] = s;
    }
    __syncthreads();

    // ---- P2: expand + residual (fea from regs), We via wave-uniform LDS ----
    float cf[16];
    #pragma unroll
    for (int o = 0; o < 16; ++o) cf[o] = lPart[o*64 + xl];

    const int xg = 2*i + px;
    const int yg = 2*j + py;
    float* op = out + ((size_t)(b*Cc)*H2c + yg)*W2c + xg;

    #pragma unroll
    for (int kk = 0; kk < 32; ++kk) {
        const int c = grp*32 + kk;
        const float4* wq = reinterpret_cast<const float4*>(lWe + c*16);  // wave-uniform
        const float4 q0 = wq[0], q1 = wq[1], q2 = wq[2], q3 = wq[3];
        float acc = fea[kk]
            + q0.x*cf[ 0] + q0.y*cf[ 1] + q0.z*cf[ 2] + q0.w*cf[ 3]
            + q1.x*cf[ 4] + q1.y*cf[ 5] + q1.z*cf[ 6] + q1.w*cf[ 7]
            + q2.x*cf[ 8] + q2.y*cf[ 9] + q2.z*cf[10] + q2.w*cf[11]
            + q3.x*cf[12] + q3.y*cf[13] + q3.z*cf[14] + q3.w*cf[15];
        op[(size_t)c*(H2c*W2c)] = acc;
    }
}

extern "C" void kernel_launch(void* const* d_in, const int* in_sizes, int n_in,
                              void* d_out, int out_size, void* d_ws, size_t ws_size,
                              hipStream_t stream) {
    const float* x     = (const float*)d_in[0];
    const float* wcomp = (const float*)d_in[1];
    const float* wexp  = (const float*)d_in[2];
    const float* bw1   = (const float*)d_in[3];
    const float* bb1   = (const float*)d_in[4];
    const float* bw2   = (const float*)d_in[5];
    const float* bb2   = (const float*)d_in[6];
    const float* rw    = (const float*)d_in[7];
    const float* rb    = (const float*)d_in[8];
    const float* ow    = (const float*)d_in[9];
    const float* ob    = (const float*)d_in[10];
    float* out = (float*)d_out;
    float* ws  = (float*)d_ws;   // ~66 KB

    k1_mix<<<64, 256, 0, stream>>>(wcomp, wexp, bw1, bb1, bw2, bb2, rw, rb, ow, ob, ws);
    k2_fused<<<2304, 256, 0, stream>>>(x, ws, out);
}